// Round 12
// baseline (100.591 us; speedup 1.0000x reference)
//
#include <hip/hip_runtime.h>

// Exact decision boundary for  RN_f32(inter/uni) > (float)0.7 :
//   c = 0.7f = 0x3f333333, succ(c) = 0x3f333334 (even mantissa).
//   RN(x) > c  <=>  x >= M  where M = (c + succ(c))/2 (tie rounds to even
//   = succ(c) > c, so ">=" is correct).  M = 23488103 * 2^-25 (25 sig bits),
//   uni has <=24 sig bits  =>  M*(double)uni is EXACT, comparison is exact.
//   uni >= 2 always here (every box area >= 1), so uni==0 never occurs.
#define M_BOUND 0.7000000178813934326171875

__device__ __forceinline__ unsigned long long make_key(unsigned int sbits,
                                                       unsigned int idx) {
    // descending score, ascending index tie-break (stable argsort(-score))
    return (((unsigned long long)(~sbits)) << 32) | idx;
}

// ---------------------------------------------------------------------------
// Init: zero the 32 per-column tickets (runs every launch; also cleans the
// 0xAA poison on the very first call).
// ---------------------------------------------------------------------------
__global__ __launch_bounds__(64)
void nms_init(unsigned int* __restrict__ colcnt)
{
    colcnt[threadIdx.x & 31] = 0u;   // 64 threads, 32 slots (dup write benign)
}

// ---------------------------------------------------------------------------
// Main: ONE kernel does everything.
// grid = (nb, nb) = (32, 32) full-square tile pairs, block = 256.
// Per block (bi, bj): stage i-tile (box, area, key) in LDS; wave w owns
// k in [w*64, w*64+64); lane owns 4 j's (m*64+l).
// Per pair: dir = key_i < key_j  (exact sorted-order incl. stable tie-break;
// self-pairs vanish).  c[m] += dir accumulates the argsort rank; sup[m] |=
// IoU-hit && dir.  Diet inner loop (r11): 0.69-prescaled areas, fmax-reduced
// filter, ONE __any-gated exact-f64 block per k-iter.
// Epilogue: LDS-reduce 4 wave partials, pack (supcount<<16)|rank into u32,
// write part[bi*N + j].  Then per-column last-block ticket: the 32nd block
// of column bj sums the 32 partials per j and writes the final scattered
// output -- finalize fused, no extra dispatch, no grid-wide sync.
// d_out layout: [N*4 floats boxes][N floats keep], scattered to rank slots.
// ---------------------------------------------------------------------------
__global__ __launch_bounds__(256)
void nms_main(const float4* __restrict__ bbox,
              const float* __restrict__ score,
              unsigned int* __restrict__ part,
              unsigned int* __restrict__ colcnt,
              float* __restrict__ out, int N)
{
    __shared__ __align__(16) char smem_raw[256 * 16 + 256 * 4 + 256 * 8];
    __shared__ unsigned int sticket;
    float4*             tile  = (float4*)smem_raw;
    float*              tarea = (float*)(smem_raw + 256 * 16);
    unsigned long long* tkey  = (unsigned long long*)(smem_raw + 256 * 20);

    const int bi  = blockIdx.x;
    const int bj  = blockIdx.y;
    const int tid = threadIdx.x;
    const int w   = tid >> 6;
    const int l   = tid & 63;

    {
        const int i = bi * 256 + tid;
        const float4 bb = bbox[i];
        tile[tid]  = bb;
        tarea[tid] = (bb.z - bb.x) * (bb.w - bb.y);   // single-rounded, as np
        tkey[tid]  = make_key(__float_as_uint(score[i]), (unsigned int)i);
    }

    float4             jb[4];
    float              aj[4], paj[4];
    unsigned long long jkey[4];
    #pragma unroll
    for (int m = 0; m < 4; ++m) {
        const int j = bj * 256 + m * 64 + l;
        jb[m]   = bbox[j];
        aj[m]   = (jb[m].z - jb[m].x) * (jb[m].w - jb[m].y);
        paj[m]  = 0.69f * aj[m];
        jkey[m] = make_key(__float_as_uint(score[j]), (unsigned int)j);
    }
    __syncthreads();

    unsigned int c[4]   = {0u, 0u, 0u, 0u};
    unsigned int sup[4] = {0u, 0u, 0u, 0u};
    const int kbase = w * 64;

    #pragma unroll 4
    for (int k = 0; k < 64; ++k) {
        const float4             bo  = tile[kbase + k];
        const float              ai  = tarea[kbase + k];
        const float              pai = 0.69f * ai;
        const unsigned long long ik  = tkey[kbase + k];

        float inter[4], f[4];
        bool  dir[4];
        #pragma unroll
        for (int m = 0; m < 4; ++m) {
            const float iy1 = fmaxf(bo.x, jb[m].x);
            const float ix1 = fmaxf(bo.y, jb[m].y);
            const float iy2 = fminf(bo.z, jb[m].z);
            const float ix2 = fminf(bo.w, jb[m].w);
            const float ih  = fmaxf(iy2 - iy1, 0.0f);
            const float iw  = fmaxf(ix2 - ix1, 0.0f);
            inter[m] = ih * iw;
            // conservative filter ~ iou > 0.690 (true cut 0.7, margin 1e-2
            // >> accumulated rounding): no true hit can be skipped.
            f[m]   = fmaf(1.69f, inter[m], -(pai + paj[m]));
            dir[m] = (ik < jkey[m]);            // i precedes j (exact)
            c[m] += dir[m] ? 1u : 0u;           // rank accumulation
        }
        const float anyv = fmaxf(fmaxf(f[0], f[1]), fmaxf(f[2], f[3]));
        if (__any(anyv > 0.0f)) {               // one scalar branch per k
            #pragma unroll
            for (int m = 0; m < 4; ++m) {
                float it = inter[m];
                asm volatile("" : "+v"(it));    // block (s - ih*iw) -> fma
                const float s   = ai + aj[m];   // exact: single-rounded
                const float uni = s - it;
                const bool hit  = ((double)it >= M_BOUND * (double)uni);
                sup[m] |= (hit && dir[m]) ? 1u : 0u;
            }
        }
    }

    // epilogue: reduce 4 wave-partials per j; pack (sup<<16) | count.
    // block rank-sum <= 256 (low16 safe); column sup-sum <= 32*4 -> <2^8
    // in high16; column rank-sum <= 8191 < 2^16: no carry between fields.
    __syncthreads();
    unsigned int* red = (unsigned int*)smem_raw;     // reuse tile LDS
    #pragma unroll
    for (int m = 0; m < 4; ++m)
        red[w * 256 + m * 64 + l] = (sup[m] ? 0x10000u : 0u) + c[m];
    __syncthreads();
    const unsigned int tot = red[tid] + red[256 + tid] +
                             red[512 + tid] + red[768 + tid];
    part[(size_t)bi * N + bj * 256 + tid] = tot;

    // per-column last-block finalize (deterministic: the winner reads the
    // same completed data whichever block it is; ranks are a permutation,
    // so finalizer writes are disjoint across columns).
    __threadfence();                                  // release part[]
    if (tid == 0) sticket = atomicAdd(&colcnt[bj], 1u);
    __syncthreads();
    if (sticket == (unsigned int)(gridDim.x - 1)) {
        __threadfence();                              // acquire part[]
        const int j = bj * 256 + tid;
        unsigned int t2 = 0;
        #pragma unroll 8
        for (int b = 0; b < 32; ++b)
            t2 += part[(size_t)b * N + j];
        const unsigned int r = t2 & 0xFFFFu;          // sorted position of j
        const float s = (t2 >> 16) ? 0.0f : 1.0f;     // keep flag
        const float4 bx = bbox[j];
        float4 o;
        o.x = bx.x * s; o.y = bx.y * s; o.z = bx.z * s; o.w = bx.w * s;
        ((float4*)out)[r] = o;
        out[N * 4 + r] = s;
    }
}

extern "C" void kernel_launch(void* const* d_in, const int* in_sizes, int n_in,
                              void* d_out, int out_size, void* d_ws, size_t ws_size,
                              hipStream_t stream) {
    const float* bbox  = (const float*)d_in[0];   // [1, N, 4] (y1,x1,y2,x2)
    const float* score = (const float*)d_in[1];   // [1, N]
    const int N = in_sizes[1];                    // 8192
    const int nb = N / 256;                       // 32

    unsigned int* part   = (unsigned int*)d_ws;                         // nb*N*4 = 1 MB
    unsigned int* colcnt = (unsigned int*)((char*)d_ws +
                                           (size_t)nb * N * 4);         // 128 B

    nms_init<<<1, 64, 0, stream>>>(colcnt);
    nms_main<<<dim3(nb, nb), 256, 0, stream>>>((const float4*)bbox, score,
                                               part, colcnt,
                                               (float*)d_out, N);
}

// Round 13
// 40.277 us; speedup vs baseline: 2.4975x; 2.4975x over previous
//
#include <hip/hip_runtime.h>

// Exact decision boundary for  RN_f32(inter/uni) > (float)0.7 :
//   c = 0.7f = 0x3f333333, succ(c) = 0x3f333334 (even mantissa).
//   RN(x) > c  <=>  x >= M  where M = (c + succ(c))/2 (tie rounds to even
//   = succ(c) > c, so ">=" is correct).  M = 23488103 * 2^-25 (25 sig bits),
//   uni has <=24 sig bits  =>  M*(double)uni is EXACT, comparison is exact.
//   uni >= 2 always here (every box area >= 1), so uni==0 never occurs.
#define M_BOUND 0.7000000178813934326171875

__device__ __forceinline__ unsigned long long make_key(unsigned int sbits,
                                                       unsigned int idx) {
    // descending score, ascending index tie-break (stable argsort(-score))
    return (((unsigned long long)(~sbits)) << 32) | idx;
}

// ---------------------------------------------------------------------------
// Kernel 1: TRIANGULAR TWO-SIDED pair kernel.  grid = 528 tile-pairs
// (bi <= bj), block = 256.  Stage i-tile (box,area,key) in LDS; wave w owns
// i-slots [w*64, w*64+64); per k, the wave's 64 lanes x 4 m cover ALL 256
// j's of tile bj.  dir = key_i < key_j (exact order, stable tie-break).
//   j-side (per lane): c[m] += dir; sup[m] |= hit && dir.
//   i-side (per k, off-diag only, wave-uniform): cnt_i = 256 - sum_m
//     popc(ballot(dir[m])); sup_i = any_m any_lane(hit && !dir[m]).
// Diagonal tiles enumerate every ordered pair, so j-side alone covers both
// directions (self-pairs vanish: dir(i,i)=false); i-side skipped (no
// double-count).  Partials: part[bi*N + j] from j-side, part[bj*N + i]
// from i-side -> every (row, col) cell of the 32xN matrix written once.
// Diet inner loop (r11): prescaled areas, fmax-reduced conservative filter
// (~iou>0.690 vs true cut 0.7, margin 1e-2 >> rounding), ONE __any-gated
// exact-f64 block per k-iter.
// ---------------------------------------------------------------------------
__global__ __launch_bounds__(256)
void nms_tri(const float4* __restrict__ bbox,
             const float* __restrict__ score,
             unsigned int* __restrict__ part, int N)
{
    __shared__ __align__(16) char smem_raw[256 * 16 + 256 * 4 + 256 * 8];
    __shared__ unsigned int ldsI[256];
    float4*             tile  = (float4*)smem_raw;
    float*              tarea = (float*)(smem_raw + 256 * 16);
    unsigned long long* tkey  = (unsigned long long*)(smem_raw + 256 * 20);

    // decode triangular index: x = bj*(bj+1)/2 + bi, bi <= bj
    const int x = blockIdx.x;
    int bj = (int)((sqrtf(8.0f * (float)x + 1.0f) - 1.0f) * 0.5f);
    while ((bj + 1) * (bj + 2) / 2 <= x) ++bj;
    while (bj * (bj + 1) / 2 > x) --bj;
    const int bi = x - bj * (bj + 1) / 2;

    const int tid = threadIdx.x;
    const int w   = tid >> 6;
    const int l   = tid & 63;
    const bool offdiag = (bi < bj);

    {
        const int i = bi * 256 + tid;
        const float4 bb = bbox[i];
        tile[tid]  = bb;
        tarea[tid] = (bb.z - bb.x) * (bb.w - bb.y);   // single-rounded, as np
        tkey[tid]  = make_key(__float_as_uint(score[i]), (unsigned int)i);
    }

    float4             jb[4];
    float              aj[4], paj[4];
    unsigned long long jkey[4];
    #pragma unroll
    for (int m = 0; m < 4; ++m) {
        const int j = bj * 256 + m * 64 + l;
        jb[m]   = bbox[j];
        aj[m]   = (jb[m].z - jb[m].x) * (jb[m].w - jb[m].y);
        paj[m]  = 0.69f * aj[m];
        jkey[m] = make_key(__float_as_uint(score[j]), (unsigned int)j);
    }
    __syncthreads();

    unsigned int c[4]   = {0u, 0u, 0u, 0u};
    unsigned int sup[4] = {0u, 0u, 0u, 0u};
    const int kbase = w * 64;

    #pragma unroll 4
    for (int k = 0; k < 64; ++k) {
        const float4             bo  = tile[kbase + k];
        const float              ai  = tarea[kbase + k];
        const float              pai = 0.69f * ai;
        const unsigned long long ik  = tkey[kbase + k];

        float inter[4], f[4];
        bool  dir[4];
        #pragma unroll
        for (int m = 0; m < 4; ++m) {
            const float iy1 = fmaxf(bo.x, jb[m].x);
            const float ix1 = fmaxf(bo.y, jb[m].y);
            const float iy2 = fminf(bo.z, jb[m].z);
            const float ix2 = fminf(bo.w, jb[m].w);
            const float ih  = fmaxf(iy2 - iy1, 0.0f);
            const float iw  = fmaxf(ix2 - ix1, 0.0f);
            inter[m] = ih * iw;
            f[m]     = fmaf(1.69f, inter[m], -(pai + paj[m]));
            dir[m]   = (ik < jkey[m]);          // i precedes j (exact)
            c[m] += dir[m] ? 1u : 0u;           // rank_j accumulation
        }

        // i-side count (off-diag only): this k's i meets all 256 j's here.
        unsigned int cntI = 0u;
        if (offdiag) {
            cntI = 256u - (unsigned int)(__popcll(__ballot(dir[0])) +
                                         __popcll(__ballot(dir[1])) +
                                         __popcll(__ballot(dir[2])) +
                                         __popcll(__ballot(dir[3])));
        }

        bool supI = false;
        const float anyv = fmaxf(fmaxf(f[0], f[1]), fmaxf(f[2], f[3]));
        if (__any(anyv > 0.0f)) {               // one scalar branch per k
            #pragma unroll
            for (int m = 0; m < 4; ++m) {
                float it = inter[m];
                asm volatile("" : "+v"(it));    // block (s - ih*iw) -> fma
                const float s   = ai + aj[m];   // exact: single-rounded
                const float uni = s - it;
                const bool hit  = ((double)it >= M_BOUND * (double)uni);
                sup[m] |= (hit && dir[m]) ? 1u : 0u;
                supI = supI || __any(hit && !dir[m]);
            }
        }
        if (offdiag && l == 0)
            ldsI[kbase + k] = (supI ? 0x10000u : 0u) + cntI;
    }

    // epilogue: j-side reduce (4 wave partials per j), pack (sup<<16)|rank.
    // rank column-sum <= 8191 < 2^16 (no carry); sup column-sum < 2^24.
    __syncthreads();
    unsigned int* red = (unsigned int*)smem_raw;     // reuse tile LDS
    #pragma unroll
    for (int m = 0; m < 4; ++m)
        red[w * 256 + m * 64 + l] = (sup[m] ? 0x10000u : 0u) + c[m];
    __syncthreads();
    const unsigned int tot = red[tid] + red[256 + tid] +
                             red[512 + tid] + red[768 + tid];
    part[(size_t)bi * N + bj * 256 + tid] = tot;
    if (offdiag)
        part[(size_t)bj * N + bi * 256 + tid] = ldsI[tid];
}

// ---------------------------------------------------------------------------
// Kernel 2: finalize.  tot = sum of 32 row-partials per box:
// rank = tot & 0xFFFF (exact sorted position), suppressed = (tot>>16) != 0.
// Scatter masked box + keep flag to the rank slot.
// d_out layout: [N*4 floats boxes][N floats keep].
// ---------------------------------------------------------------------------
__global__ __launch_bounds__(256)
void nms_finalize(const float4* __restrict__ bbox,
                  const unsigned int* __restrict__ part,
                  float* __restrict__ out, int N)
{
    const int j = blockIdx.x * 256 + threadIdx.x;
    unsigned int tot = 0;
    #pragma unroll 8
    for (int b = 0; b < 32; ++b)
        tot += part[(size_t)b * N + j];
    const unsigned int r = tot & 0xFFFFu;
    const float s = (tot >> 16) ? 0.0f : 1.0f;
    const float4 bx = bbox[j];
    float4 o;
    o.x = bx.x * s; o.y = bx.y * s; o.z = bx.z * s; o.w = bx.w * s;
    ((float4*)out)[r] = o;
    out[N * 4 + r] = s;
}

extern "C" void kernel_launch(void* const* d_in, const int* in_sizes, int n_in,
                              void* d_out, int out_size, void* d_ws, size_t ws_size,
                              hipStream_t stream) {
    const float* bbox  = (const float*)d_in[0];   // [1, N, 4] (y1,x1,y2,x2)
    const float* score = (const float*)d_in[1];   // [1, N]
    const int N = in_sizes[1];                    // 8192
    const int nb = N / 256;                       // 32

    unsigned int* part = (unsigned int*)d_ws;     // nb * N * 4 B = 1 MB

    nms_tri<<<nb * (nb + 1) / 2, 256, 0, stream>>>((const float4*)bbox, score,
                                                   part, N);
    nms_finalize<<<nb, 256, 0, stream>>>((const float4*)bbox, part,
                                         (float*)d_out, N);
}

// Round 14
// 39.313 us; speedup vs baseline: 2.5587x; 1.0245x over previous
//
#include <hip/hip_runtime.h>

// Exact decision boundary for  RN_f32(inter/uni) > (float)0.7 :
//   c = 0.7f = 0x3f333333, succ(c) = 0x3f333334 (even mantissa).
//   RN(x) > c  <=>  x >= M  where M = (c + succ(c))/2 (tie rounds to even
//   = succ(c) > c, so ">=" is correct).  M = 23488103 * 2^-25 (25 sig bits),
//   uni has <=24 sig bits  =>  M*(double)uni is EXACT, comparison is exact.
//   uni >= 2 always here (every box area >= 1), so uni==0 never occurs.
#define M_BOUND 0.7000000178813934326171875

__device__ __forceinline__ unsigned long long make_key(unsigned int sbits,
                                                       unsigned int idx) {
    // descending score, ascending index tie-break (stable argsort(-score))
    return (((unsigned long long)(~sbits)) << 32) | idx;
}

// ---------------------------------------------------------------------------
// Kernel A: partial rank counts, 2 i-keys per thread, LDS-staged key tile,
// no atomics.  grid = (N/512, N/256) = 512 blocks -> 2 blocks/CU.
// partial[y][i] = #{keys in y-tile < key_i}   (each cell written once)
// ---------------------------------------------------------------------------
__global__ __launch_bounds__(256)
void nms_rank_partial(const float* __restrict__ score,
                      unsigned int* __restrict__ partial, int N)
{
    __shared__ unsigned long long skeys[256];
    const int tid = threadIdx.x;
    const int y   = blockIdx.y;
    const int t   = y * 256 + tid;
    skeys[tid] = make_key(__float_as_uint(score[t]), (unsigned int)t);

    const int i0 = blockIdx.x * 512 + tid;
    const unsigned long long k0 = make_key(__float_as_uint(score[i0      ]), i0      );
    const unsigned long long k1 = make_key(__float_as_uint(score[i0 + 256]), i0 + 256);
    __syncthreads();

    unsigned int c0 = 0, c1 = 0;
    #pragma unroll 16
    for (int k = 0; k < 256; ++k) {
        const unsigned long long ok = skeys[k];
        c0 += (ok < k0) ? 1u : 0u;
        c1 += (ok < k1) ? 1u : 0u;
    }
    unsigned int* row = partial + (size_t)y * N;
    row[i0      ] = c0;
    row[i0 + 256] = c1;
}

// ---------------------------------------------------------------------------
// Kernel B: reduce partial ranks (32 independent coalesced loads), scatter
// box + area to sorted slot, zero the suppression mask.
// ---------------------------------------------------------------------------
__global__ __launch_bounds__(256)
void nms_scatter(const float4* __restrict__ bbox,
                 const unsigned int* __restrict__ partial,
                 float4* __restrict__ sortedBox,
                 float* __restrict__ sortedArea,
                 unsigned int* __restrict__ mask, int N)
{
    const int i = blockIdx.x * 256 + threadIdx.x;
    const int ny = N / 256;
    unsigned int r = 0;
    #pragma unroll 8
    for (int y = 0; y < ny; ++y)
        r += partial[(size_t)y * N + i];
    const float4 b = bbox[i];
    sortedBox[r]  = b;
    sortedArea[r] = (b.z - b.x) * (b.w - b.y);   // (y2-y1)*(x2-x1), once (as np)
    mask[i] = 0u;
}

// ---------------------------------------------------------------------------
// Kernel C: suppressed[j] |= any i<j with IoU > 0.7.  VALU-diet body:
// ~12 dynamic VALU instrs/pair; ONE v_cmp + scalar branch per k-iter
// (filter max-reduced over the 4 m's).  Exact f64 boundary compare + diag
// i<j predicate live only in the rarely-taken wave-uniform branch.
// Filter: fires iff 1.69*inter > 0.69*ai + 0.69*aj ~ iou > 0.690; true
// hits need iou > 0.7 -> margin ~1e-2 >> accumulated rounding:
// conservative, no hit skipped.
// 1D triangular grid (bi <= bj); 4 waves split the i-tile; lane owns 4 j's.
// ---------------------------------------------------------------------------
__global__ __launch_bounds__(256)
void nms_suppress(const float4* __restrict__ sortedBox,
                  const float* __restrict__ sortedArea,
                  unsigned int* __restrict__ mask)
{
    // decode triangular index: x = bj*(bj+1)/2 + bi, bi <= bj
    const int x = blockIdx.x;
    int bj = (int)((sqrtf(8.0f * (float)x + 1.0f) - 1.0f) * 0.5f);
    while ((bj + 1) * (bj + 2) / 2 <= x) ++bj;
    while (bj * (bj + 1) / 2 > x) --bj;
    const int bi = x - bj * (bj + 1) / 2;

    __shared__ float4 tile[256];
    __shared__ float  tarea[256];
    const int tid = threadIdx.x;

    tile[tid]  = sortedBox[bi * 256 + tid];
    tarea[tid] = sortedArea[bi * 256 + tid];
    __syncthreads();

    const int w = tid >> 6;           // wave id: k-quarter of the i-tile
    const int l = tid & 63;
    const bool offdiag = (bi < bj);

    float4 jb[4];
    float  aj[4];
    float  paj[4];
    #pragma unroll
    for (int m = 0; m < 4; ++m) {
        const int j = bj * 256 + m * 64 + l;
        jb[m]  = sortedBox[j];
        aj[m]  = sortedArea[j];
        paj[m] = 0.69f * aj[m];
    }

    unsigned int sup[4] = {0u, 0u, 0u, 0u};
    const int kbase = w * 64;
    #pragma unroll 4
    for (int k = 0; k < 64; ++k) {
        const float4 bo  = tile[kbase + k];
        const float  ai  = tarea[kbase + k];
        const float  pai = 0.69f * ai;        // 1 instr per k (1/4 per pair)
        const int    ig  = kbase + k;         // local i index within tile

        float inter[4], f[4];
        #pragma unroll
        for (int m = 0; m < 4; ++m) {
            const float iy1 = fmaxf(bo.x, jb[m].x);
            const float ix1 = fmaxf(bo.y, jb[m].y);
            const float iy2 = fminf(bo.z, jb[m].z);
            const float ix2 = fminf(bo.w, jb[m].w);
            const float ih  = fmaxf(iy2 - iy1, 0.0f);
            const float iw  = fmaxf(ix2 - ix1, 0.0f);
            inter[m] = ih * iw;
            f[m] = fmaf(1.69f, inter[m], -(pai + paj[m]));
        }
        const float anyv = fmaxf(fmaxf(f[0], f[1]), fmaxf(f[2], f[3]));
        if (__any(anyv > 0.0f)) {             // one scalar branch per k-iter
            #pragma unroll
            for (int m = 0; m < 4; ++m) {
                float it = inter[m];
                asm volatile("" : "+v"(it));  // block (s - ih*iw) -> fma
                const float s   = ai + aj[m]; // exact path: single-rounded
                const float uni = s - it;
                const bool hit  = ((double)it >= M_BOUND * (double)uni);
                const bool pred = offdiag || (ig < m * 64 + l);  // i<j on diag
                sup[m] |= (hit && pred) ? 1u : 0u;
            }
        }
    }
    #pragma unroll
    for (int m = 0; m < 4; ++m)
        if (sup[m]) atomicOr(&mask[bj * 256 + m * 64 + l], 1u);
}

// ---------------------------------------------------------------------------
// Kernel D: keep = !suppressed; write masked sorted boxes + keep flags.
// d_out layout: [N*4 floats boxes][N floats keep].
// ---------------------------------------------------------------------------
__global__ __launch_bounds__(256)
void nms_output(const float4* __restrict__ sortedBox,
                const unsigned int* __restrict__ mask,
                float* __restrict__ out, int N)
{
    const int j = blockIdx.x * 256 + threadIdx.x;
    const float s = (mask[j] == 0u) ? 1.0f : 0.0f;
    const float4 b = sortedBox[j];
    float4 o;
    o.x = b.x * s; o.y = b.y * s; o.z = b.z * s; o.w = b.w * s;
    ((float4*)out)[j] = o;
    out[N * 4 + j] = s;
}

extern "C" void kernel_launch(void* const* d_in, const int* in_sizes, int n_in,
                              void* d_out, int out_size, void* d_ws, size_t ws_size,
                              hipStream_t stream) {
    const float* bbox  = (const float*)d_in[0];   // [1, N, 4] (y1,x1,y2,x2)
    const float* score = (const float*)d_in[1];   // [1, N]
    const int N = in_sizes[1];                    // 8192
    const int nb = N / 256;                       // 32

    char* ws = (char*)d_ws;
    float4*       sortedBox  = (float4*)ws;                               // N*16 B
    float*        sortedArea = (float*)(ws + (size_t)N * 16);             // N*4 B
    unsigned int* mask       = (unsigned int*)(ws + (size_t)N * 20);      // N*4 B
    unsigned int* partial    = (unsigned int*)(ws + (size_t)N * 24);      // nb*N*4 B

    nms_rank_partial<<<dim3(N / 512, nb), 256, 0, stream>>>(score, partial, N);
    nms_scatter<<<nb, 256, 0, stream>>>((const float4*)bbox, partial,
                                        sortedBox, sortedArea, mask, N);
    nms_suppress<<<nb * (nb + 1) / 2, 256, 0, stream>>>(sortedBox, sortedArea,
                                                        mask);
    nms_output<<<nb, 256, 0, stream>>>(sortedBox, mask, (float*)d_out, N);
}